// Round 1
// 151.606 us; speedup vs baseline: 1.0631x; 1.0631x over previous
//
#include <hip/hip_runtime.h>
#include <math.h>

#define NVEC 2016
#define NT   256
#define KMAX 8

typedef __attribute__((ext_vector_type(8))) short short8;
typedef __attribute__((ext_vector_type(4))) float v4f;

#define MFMA(a,b,c) __builtin_amdgcn_mfma_f32_16x16x32_bf16((a),(b),(c),0,0,0)

// packed RNE f32->bf16 x2 in one instruction: lo16 = bf16(a), hi16 = bf16(b)
static __device__ __forceinline__ unsigned cvtpk(float a, float b){
    unsigned r;
    asm("v_cvt_pk_bf16_f32 %0, %1, %2" : "=v"(r) : "v"(a), "v"(b));
    return r;
}

// 4 floats -> h-plane uint2 (RNE bf16) + l-plane uint2 (RNE bf16 of exact residual).
// h = RNE(x), r = x - float(h) exact, l = RNE(r): pair rel err ~2^-25.
static __device__ __forceinline__ void pack_hl4(const float x[4], uint2 &H, uint2 &L){
    H.x = cvtpk(x[0], x[1]);
    H.y = cvtpk(x[2], x[3]);
    float r0 = x[0] - __uint_as_float(H.x << 16);
    float r1 = x[1] - __uint_as_float(H.x & 0xFFFF0000u);
    float r2 = x[2] - __uint_as_float(H.y << 16);
    float r3 = x[3] - __uint_as_float(H.y & 0xFFFF0000u);
    L.x = cvtpk(r0, r1);
    L.y = cvtpk(r2, r3);
}

// XOR-swizzled plane: 64 majors x 64 shorts (128B row = 8 x 16B granules).
// phys granule = g ^ (maj&7): col accesses spread across all banks.
static __device__ __forceinline__ int swz(int maj, int g){ return maj*64 + ((g ^ (maj & 7)) << 3); }
static __device__ __forceinline__ int swe(int maj, int t){ return swz(maj, t >> 3) + (t & 7); }

static __device__ __forceinline__ short8 ldp(const unsigned short* P, int maj, int off){
    return *(const short8*)&P[swz(maj, off >> 3)];
}

static __device__ __forceinline__ short8 neg8(short8 a){
    union { unsigned u[4]; short8 s; } X; X.s = a;
    X.u[0]^=0x80008000u; X.u[1]^=0x80008000u; X.u[2]^=0x80008000u; X.u[3]^=0x80008000u;
    return X.s;
}

// 4 consecutive rows of column cc as f32 (h+l planes)
static __device__ __forceinline__ void pair4(const unsigned short* Ph, const unsigned short* Pl,
                                             int cc, int row0, float o[4]){
    const int base = swe(cc, row0);
    uint2 h = *(const uint2*)&Ph[base];
    uint2 l = *(const uint2*)&Pl[base];
    o[0] = __uint_as_float(h.x<<16)           + __uint_as_float(l.x<<16);
    o[1] = __uint_as_float(h.x & 0xFFFF0000u) + __uint_as_float(l.x & 0xFFFF0000u);
    o[2] = __uint_as_float(h.y<<16)           + __uint_as_float(l.y<<16);
    o[3] = __uint_as_float(h.y & 0xFFFF0000u) + __uint_as_float(l.y & 0xFFFF0000u);
}

static __device__ __forceinline__ void pair4h(const unsigned short* Ph, int cc, int row0, float o[4]){
    const uint2 h = *(const uint2*)&Ph[swe(cc, row0)];
    o[0] = __uint_as_float(h.x<<16);
    o[1] = __uint_as_float(h.x & 0xFFFF0000u);
    o[2] = __uint_as_float(h.y<<16);
    o[3] = __uint_as_float(h.y & 0xFFFF0000u);
}

__global__ void __launch_bounds__(NT, 4)
SkewSymMatrixExp_kernel(const float* __restrict__ vin, float* __restrict__ out)
{
    // 5 planes x 8192 B = 40960 B exactly -> 4 blocks/CU
    __shared__ __attribute__((aligned(16))) unsigned short PAh[4096]; // A col -> V col -> Xc h
    __shared__ __attribute__((aligned(16))) unsigned short PAl[4096]; // A col -> V col -> Xc l
    __shared__ __attribute__((aligned(16))) unsigned short P2h[4096]; // A2 col -> Xr h
    __shared__ __attribute__((aligned(16))) unsigned short P2l[4096]; // A2 col -> Xr l
    __shared__ __attribute__((aligned(16))) unsigned short P4h[4096]; // scratch -> A4 (RNE h-only)

    const int tid  = threadIdx.x;
    const int wave = tid >> 6;
    const int lane = tid & 63;
    const int q    = lane >> 4;
    const int m    = lane & 15;
    const int Rw   = (wave >> 1) * 32;   // 32-row band
    const int Cw   = (wave & 1) * 32;    // 32-col band
    const float* v = vin + (size_t)blockIdx.x * NVEC;

    // ---- zero A planes ----
    {
        const uint4 z4 = make_uint4(0u,0u,0u,0u);
        for (int i = tid; i < 512; i += NT){ ((uint4*)PAh)[i] = z4; ((uint4*)PAl)[i] = z4; }
    }
    __syncthreads();

    // ---- scatter skew-symmetric A (unscaled) into col planes: P[c][r] = A[r][c] ----
    for (int p = tid; p < NVEC; p += NT) {
        int i = (int)((127.0f - sqrtf(16129.0f - 8.0f * (float)p)) * 0.5f);
        if (i < 0) i = 0;
        if (i > 62) i = 62;
        while (i > 0 && (63*i - ((i*(i-1))>>1)) > p) --i;
        while (i < 62 && (63*(i+1) - (((i+1)*i)>>1)) <= p) ++i;
        const int off = 63*i - ((i*(i-1))>>1);
        const int j = i + 1 + (p - off);
        const float x = v[p];
        const unsigned hp = cvtpk(x, x) & 0xFFFFu;
        const float    r  = x - __uint_as_float(hp << 16);
        const unsigned lp = cvtpk(r, r) & 0xFFFFu;
        PAh[swe(j, i)] = (unsigned short)(hp ^ 0x8000u);   // A[i][j] = -v
        PAl[swe(j, i)] = (unsigned short)(lp ^ 0x8000u);
        PAh[swe(i, j)] = (unsigned short)hp;               // A[j][i] = +v
        PAl[swe(i, j)] = (unsigned short)lp;
    }
    __syncthreads();

    // ---- cache A-op fragments in registers (live through R4) ----
    short8 Ah[2][2], Al[2][2];
#pragma unroll
    for (int i=0;i<2;++i)
#pragma unroll
        for (int c=0;c<2;++c){
            Ah[i][c] = neg8(ldp(PAh, Rw+16*i+m, 32*c+8*q));   // A[r][k] = -P[r][k]
            Al[i][c] = neg8(ldp(PAl, Rw+16*i+m, 32*c+8*q));
        }

    v4f acc[2][2];

    // ---- R1: A2 = A*A (unscaled) -> P2 h/l ----
#pragma unroll
    for (int i=0;i<2;++i)
#pragma unroll
        for (int j=0;j<2;++j) acc[i][j] = (v4f){0.f,0.f,0.f,0.f};
#pragma unroll
    for (int c=0;c<2;++c)
#pragma unroll
        for (int j=0;j<2;++j){
            short8 bh = ldp(PAh, Cw+16*j+m, 32*c+8*q);
            short8 bl = ldp(PAl, Cw+16*j+m, 32*c+8*q);
#pragma unroll
            for (int i=0;i<2;++i){
                acc[i][j] = MFMA(Ah[i][c], bh, acc[i][j]);
                acc[i][j] = MFMA(Al[i][c], bh, acc[i][j]);
                acc[i][j] = MFMA(Ah[i][c], bl, acc[i][j]);
            }
        }
#pragma unroll
    for (int i=0;i<2;++i)
#pragma unroll
        for (int j=0;j<2;++j){
            const int row0 = Rw+16*i+4*q, cc = Cw+16*j+m;
            const float x4[4] = { acc[i][j][0], acc[i][j][1], acc[i][j][2], acc[i][j][3] };
            uint2 H, L; pack_hl4(x4, H, L);
            const int base = swe(cc, row0);
            *(uint2*)&P2h[base] = H;
            *(uint2*)&P2l[base] = L;
        }
    __syncthreads();

    // ---- k from ||A2||_1 (scratch aliases P4h; every wave reduces redundantly) ----
    float* scratch = (float*)P4h;
    {
        const int c0 = tid & 63, seg = tid >> 6;
        float s = 0.f;
#pragma unroll
        for (int gg=0; gg<2; ++gg){
            const uint4 w = *(const uint4*)&P2h[swz(c0, 2*seg+gg)];
            const unsigned ws[4] = {w.x, w.y, w.z, w.w};
#pragma unroll
            for (int e=0;e<4;++e){
                s += __uint_as_float((ws[e] & 0x7FFFu) << 16);
                s += __uint_as_float(ws[e] & 0x7FFF0000u);
            }
        }
        scratch[tid] = s;
    }
    __syncthreads();
    int kq; float s1, s2, s4;
    {
        float s = scratch[lane] + scratch[lane+64] + scratch[lane+128] + scratch[lane+192];
#pragma unroll
        for (int o=1;o<64;o<<=1) s = fmaxf(s, __shfl_xor(s, o, 64));
        float est = sqrtf(s) * 0.625f;          // sqrt(||A2||_1)/theta, theta=1.6
        kq = 0;
        if (est > 1.f) kq = (int)ceilf(log2f(est));
        if (kq > KMAX) kq = KMAX;
        s1 = exp2f(-(float)kq);                 // B = s1*A
        s2 = s1*s1; s4 = s2*s2;
    }
    __syncthreads();                            // all scratch reads done before P4h writes

    // ---- R2: A4 = s4 * A2*A2 (RNE bf16, h-only) -> P4h ----
#pragma unroll
    for (int i=0;i<2;++i)
#pragma unroll
        for (int j=0;j<2;++j) acc[i][j] = (v4f){0.f,0.f,0.f,0.f};
#pragma unroll
    for (int c=0;c<2;++c){
        short8 a2h[2], a2l[2];
#pragma unroll
        for (int i=0;i<2;++i){
            a2h[i] = ldp(P2h, Rw+16*i+m, 32*c+8*q);
            a2l[i] = ldp(P2l, Rw+16*i+m, 32*c+8*q);
        }
#pragma unroll
        for (int j=0;j<2;++j){
            short8 bh = ldp(P2h, Cw+16*j+m, 32*c+8*q);
            short8 bl = ldp(P2l, Cw+16*j+m, 32*c+8*q);
#pragma unroll
            for (int i=0;i<2;++i){
                acc[i][j] = MFMA(a2h[i], bh, acc[i][j]);
                acc[i][j] = MFMA(a2l[i], bh, acc[i][j]);
                acc[i][j] = MFMA(a2h[i], bl, acc[i][j]);
            }
        }
    }
#pragma unroll
    for (int i=0;i<2;++i)
#pragma unroll
        for (int j=0;j<2;++j){
            const int row0 = Rw+16*i+4*q, cc = Cw+16*j+m;
            uint2 H;
            H.x = cvtpk(s4*acc[i][j][0], s4*acc[i][j][1]);
            H.y = cvtpk(s4*acc[i][j][2], s4*acc[i][j][3]);
            *(uint2*)&P4h[swe(cc,row0)] = H;
        }
    __syncthreads();

    // ---- R3+R4 shared products: accA = A4*A2h, accB = A4*A4h (h-only operands,
    //      same MFMA budget as the two old polyf rounds; both linear combos taken in f32) ----
    v4f accA[2][2], accB[2][2];
#pragma unroll
    for (int i=0;i<2;++i)
#pragma unroll
        for (int j=0;j<2;++j){ accA[i][j] = (v4f){0.f,0.f,0.f,0.f}; accB[i][j] = (v4f){0.f,0.f,0.f,0.f}; }
#pragma unroll
    for (int c=0;c<2;++c){
        short8 a4f[2];
#pragma unroll
        for (int i=0;i<2;++i) a4f[i] = ldp(P4h, Rw+16*i+m, 32*c+8*q);
#pragma unroll
        for (int j=0;j<2;++j){
            short8 b2 = ldp(P2h, Cw+16*j+m, 32*c+8*q);
            short8 b4 = ldp(P4h, Cw+16*j+m, 32*c+8*q);
#pragma unroll
            for (int i=0;i<2;++i){
                accA[i][j] = MFMA(a4f[i], b2, accA[i][j]);
                accB[i][j] = MFMA(a4f[i], b4, accB[i][j]);
            }
        }
    }

    // ---- R3: V = s1*( I + B2/6 + B4/120 + s2/5040*accA + 1/362880*accB ) -> PA planes ----
    {
        const float ca3 = s2*(1.f/5040.f), cb3 = 1.f/362880.f;
#pragma unroll
        for (int i=0;i<2;++i)
#pragma unroll
            for (int j=0;j<2;++j){
                const int row0 = Rw+16*i+4*q, cc = Cw+16*j+m;
                float e2[4], e4[4];
                pair4(P2h, P2l, cc, row0, e2);
                pair4h(P4h, cc, row0, e4);
                float x4[4];
#pragma unroll
                for (int r=0;r<4;++r)
                    x4[r] = s1*( ca3*accA[i][j][r] + cb3*accB[i][j][r]
                                 + e2[r]*(s2/6.f) + e4[r]*(1.f/120.f)
                                 + ((row0+r)==cc ? 1.f : 0.f) );
                uint2 H, L; pack_hl4(x4, H, L);
                const int base = swe(cc, row0);
                *(uint2*)&PAh[base] = H;
                *(uint2*)&PAl[base] = L;
            }
    }
    __syncthreads();

    // ---- R4: X = A*V + (s2/720*accA + 1/40320*accB) + (I + B2/2 + B4/24) ----
    {
        const float ca4 = s2*(1.f/720.f), cb4 = 1.f/40320.f;
#pragma unroll
        for (int i=0;i<2;++i)
#pragma unroll
            for (int j=0;j<2;++j)
#pragma unroll
                for (int r=0;r<4;++r)
                    acc[i][j][r] = ca4*accA[i][j][r] + cb4*accB[i][j][r];
    }
    // A * V (A from registers; A-regs die here)
#pragma unroll
    for (int c=0;c<2;++c)
#pragma unroll
        for (int j=0;j<2;++j){
            short8 vfh = ldp(PAh, Cw+16*j+m, 32*c+8*q);
            short8 vfl = ldp(PAl, Cw+16*j+m, 32*c+8*q);
#pragma unroll
            for (int i=0;i<2;++i){
                acc[i][j] = MFMA(Ah[i][c], vfh, acc[i][j]);
                acc[i][j] = MFMA(Al[i][c], vfh, acc[i][j]);
                acc[i][j] = MFMA(Ah[i][c], vfl, acc[i][j]);
            }
        }
    {
        float e2[2][2][4], e4[2][2][4];
#pragma unroll
        for (int i=0;i<2;++i)
#pragma unroll
            for (int j=0;j<2;++j){
                pair4(P2h, P2l, Cw+16*j+m, Rw+16*i+4*q, e2[i][j]);
                pair4h(P4h, Cw+16*j+m, Rw+16*i+4*q, e4[i][j]);
            }
        __syncthreads();   // all reads of P2/P4/V done before X overwrites

#pragma unroll
        for (int i=0;i<2;++i)
#pragma unroll
            for (int j=0;j<2;++j){
                const int row0 = Rw+16*i+4*q, cc = Cw+16*j+m;
                float x4[4];
#pragma unroll
                for (int r=0;r<4;++r)
                    x4[r] = acc[i][j][r] + e2[i][j][r]*(s2*0.5f) + e4[i][j][r]*(1.f/24.f)
                          + ((row0+r)==cc ? 1.f : 0.f);
                if (kq == 0){
                    float* po = out + (size_t)blockIdx.x * 4096;
#pragma unroll
                    for (int r=0;r<4;++r) po[(unsigned)(row0+r)*64 + cc] = x4[r];
                } else {
                    uint2 H, L; pack_hl4(x4, H, L);
                    const int base = swe(cc, row0);
                    *(uint2*)&PAh[base] = H;                                             // Xc
                    *(uint2*)&PAl[base] = L;
                    P2h[swe(row0+0, cc)] = (unsigned short)(H.x);                        // Xr
                    P2h[swe(row0+1, cc)] = (unsigned short)(H.x >> 16);
                    P2h[swe(row0+2, cc)] = (unsigned short)(H.y);
                    P2h[swe(row0+3, cc)] = (unsigned short)(H.y >> 16);
                    P2l[swe(row0+0, cc)] = (unsigned short)(L.x);
                    P2l[swe(row0+1, cc)] = (unsigned short)(L.x >> 16);
                    P2l[swe(row0+2, cc)] = (unsigned short)(L.y);
                    P2l[swe(row0+3, cc)] = (unsigned short)(L.y >> 16);
                }
            }
    }
    __syncthreads();

    // ---- kq squarings: X = X*X (Xr=P2 planes A-op, Xc=PA planes B-op) ----
#pragma unroll 1
    for (int s = 0; s < kq; ++s){
#pragma unroll
        for (int i=0;i<2;++i)
#pragma unroll
            for (int j=0;j<2;++j) acc[i][j] = (v4f){0.f,0.f,0.f,0.f};
#pragma unroll
        for (int c=0;c<2;++c){
            short8 xh[2], xl[2];
#pragma unroll
            for (int i=0;i<2;++i){
                xh[i] = ldp(P2h, Rw+16*i+m, 32*c+8*q);
                xl[i] = ldp(P2l, Rw+16*i+m, 32*c+8*q);
            }
#pragma unroll
            for (int j=0;j<2;++j){
                short8 bh = ldp(PAh, Cw+16*j+m, 32*c+8*q);
                short8 bl = ldp(PAl, Cw+16*j+m, 32*c+8*q);
#pragma unroll
                for (int i=0;i<2;++i){
                    acc[i][j] = MFMA(xh[i], bh, acc[i][j]);
                    acc[i][j] = MFMA(xl[i], bh, acc[i][j]);
                    acc[i][j] = MFMA(xh[i], bl, acc[i][j]);
                }
            }
        }
        __syncthreads();   // all reads done before overwrite

        if (s == kq-1){
            float* po = out + (size_t)blockIdx.x * 4096;
#pragma unroll
            for (int i=0;i<2;++i)
#pragma unroll
                for (int j=0;j<2;++j){
                    const int row0 = Rw+16*i+4*q, cc = Cw+16*j+m;
#pragma unroll
                    for (int r=0;r<4;++r) po[(unsigned)(row0+r)*64 + cc] = acc[i][j][r];
                }
        } else {
#pragma unroll
            for (int i=0;i<2;++i)
#pragma unroll
                for (int j=0;j<2;++j){
                    const int row0 = Rw+16*i+4*q, cc = Cw+16*j+m;
                    const float x4[4] = { acc[i][j][0], acc[i][j][1], acc[i][j][2], acc[i][j][3] };
                    uint2 H, L; pack_hl4(x4, H, L);
                    const int base = swe(cc, row0);
                    *(uint2*)&PAh[base] = H;
                    *(uint2*)&PAl[base] = L;
                    P2h[swe(row0+0, cc)] = (unsigned short)(H.x);
                    P2h[swe(row0+1, cc)] = (unsigned short)(H.x >> 16);
                    P2h[swe(row0+2, cc)] = (unsigned short)(H.y);
                    P2h[swe(row0+3, cc)] = (unsigned short)(H.y >> 16);
                    P2l[swe(row0+0, cc)] = (unsigned short)(L.x);
                    P2l[swe(row0+1, cc)] = (unsigned short)(L.x >> 16);
                    P2l[swe(row0+2, cc)] = (unsigned short)(L.y);
                    P2l[swe(row0+3, cc)] = (unsigned short)(L.y >> 16);
                }
            __syncthreads();
        }
    }
}

extern "C" void kernel_launch(void* const* d_in, const int* in_sizes, int n_in,
                              void* d_out, int out_size, void* d_ws, size_t ws_size,
                              hipStream_t stream) {
    const float* vin = (const float*)d_in[0];
    float* out = (float*)d_out;
    const int batch = in_sizes[0] / NVEC;   // 4096
    hipLaunchKernelGGL(SkewSymMatrixExp_kernel, dim3(batch), dim3(NT), 0, stream,
                       vin, out);
}